// Round 1
// baseline (3142.341 us; speedup 1.0000x reference)
//
#include <hip/hip_runtime.h>
#include <hip/hip_bf16.h>

#define N_NODES 100000
#define N_EDGES 1600000
#define F_IN    128
#define H       256
#define NHID    512
#define NOUT    256
#define G_GR    256

typedef unsigned short u16;
typedef __attribute__((ext_vector_type(8))) short s16x8;
typedef __attribute__((ext_vector_type(8))) unsigned short u16x8;
typedef __attribute__((ext_vector_type(4))) float f32x4;

__device__ __forceinline__ float bf2f(u16 u) {
    union { unsigned int i; float f; } v; v.i = ((unsigned int)u) << 16; return v.f;
}
__device__ __forceinline__ u16 f2bf(float f) {
    union { float f; unsigned int i; } v; v.f = f;
    unsigned int x = v.i;
    x += 0x7fffu + ((x >> 16) & 1u);
    return (u16)(x >> 16);
}

// ---------------- head: count deg (by dst) + outdeg (by src) + weight transposes + goff -----
#define CD_BLKS   1563                        // 4 strided edges/thread (R8 known-good form)
#define SPX_BLKS  ((N_NODES * F_IN) / 1024)   // 12500 — carried by scatter kernel
#define SELF_BLKS ((N_NODES + 1023) / 1024)   // 98 — self-loop entries into ep2
#define T1_BLKS   ((F_IN * H) / 256)
#define T2_BLKS   ((H * H) / 256)
#define T3_BLKS   ((H * H) / 256)
#define TM1_BLKS  ((H * NHID) / 256)
#define TM2_BLKS  ((NHID * NOUT) / 256)
#define HEAD_BLKS (CD_BLKS + T1_BLKS + T2_BLKS + T3_BLKS + TM1_BLKS + TM2_BLKS + 2)

__device__ __forceinline__ void transpose_split_body(const float* __restrict__ W,
        u16* __restrict__ thi, u16* __restrict__ tlo, int K, int N, int id) {
    int n = id / K, k = id - n * K;
    float f = W[(size_t)k * N + n];
    u16 h = f2bf(f);
    thi[id] = h;
    tlo[id] = f2bf(f - bf2f(h));
}

__global__ __launch_bounds__(256) void prep_head(
        const int* __restrict__ src, const int* __restrict__ dst,
        int* __restrict__ degc, int* __restrict__ srcc,
        const float* __restrict__ W1, u16* __restrict__ t1h, u16* __restrict__ t1l,
        const float* __restrict__ W2, u16* __restrict__ t2h, u16* __restrict__ t2l,
        const float* __restrict__ W3, u16* __restrict__ t3h, u16* __restrict__ t3l,
        const float* __restrict__ Wm1, u16* __restrict__ tm1h, u16* __restrict__ tm1l,
        const float* __restrict__ Wm2, u16* __restrict__ tm2h, u16* __restrict__ tm2l,
        const int* __restrict__ batch, int* __restrict__ goff) {
    int bid = blockIdx.x;
    if (bid < CD_BLKS) {
        int base = bid * 1024 + threadIdx.x;
#pragma unroll
        for (int q = 0; q < 4; q++) {
            int e = base + q * 256;
            if (e < N_EDGES) {
                atomicAdd(&degc[dst[e]], 1);
                atomicAdd(&srcc[src[e]], 1);
            }
        }
        return;
    }
    bid -= CD_BLKS;
    if (bid < T1_BLKS) {
        transpose_split_body(W1, t1h, t1l, F_IN, H, bid * 256 + threadIdx.x);
        return;
    }
    bid -= T1_BLKS;
    if (bid < T2_BLKS) {
        transpose_split_body(W2, t2h, t2l, H, H, bid * 256 + threadIdx.x);
        return;
    }
    bid -= T2_BLKS;
    if (bid < T3_BLKS) {
        transpose_split_body(W3, t3h, t3l, H, H, bid * 256 + threadIdx.x);
        return;
    }
    bid -= T3_BLKS;
    if (bid < TM1_BLKS) {
        transpose_split_body(Wm1, tm1h, tm1l, H, NHID, bid * 256 + threadIdx.x);
        return;
    }
    bid -= TM1_BLKS;
    if (bid < TM2_BLKS) {
        transpose_split_body(Wm2, tm2h, tm2l, NHID, NOUT, bid * 256 + threadIdx.x);
        return;
    }
    bid -= TM2_BLKS;
    {
        int g = bid * 256 + threadIdx.x;
        if (g > G_GR) return;
        int lo = 0, hi = N_NODES;
        while (lo < hi) {
            int mid = (lo + hi) >> 1;
            if (batch[mid] < g) lo = mid + 1; else hi = mid;
        }
        goff[g] = lo;
    }
}

// ---------------- scan (CSR rowp) ----------------
__global__ void scan_partial(const int* __restrict__ cnt, int* __restrict__ partial, int self) {
    __shared__ int s[256];
    int t = threadIdx.x;
    int i = blockIdx.x * 256 + t;
    int v = (i < N_NODES) ? cnt[i] + self : 0;
    s[t] = v; __syncthreads();
    for (int off = 128; off > 0; off >>= 1) {
        if (t < off) s[t] += s[t + off];
        __syncthreads();
    }
    if (t == 0) partial[blockIdx.x] = s[0];
}

__global__ void scan_offsets(int* __restrict__ partial, int nb, int* __restrict__ rowp, int total) {
    __shared__ int s[512];
    int t = threadIdx.x;
    int orig = (t < nb) ? partial[t] : 0;
    s[t] = orig; __syncthreads();
    for (int off = 1; off < 512; off <<= 1) {
        int u = (t >= off) ? s[t - off] : 0;
        __syncthreads();
        s[t] += u;
        __syncthreads();
    }
    if (t < nb) partial[t] = s[t] - orig;
    if (t == 0) rowp[N_NODES] = total;
}

__global__ void scan_final_dinv(const int* __restrict__ cnt, const int* __restrict__ partial,
                                int* __restrict__ rowp, int* __restrict__ cur,
                                float* __restrict__ dinv) {
    __shared__ int s[256];
    int t = threadIdx.x;
    int i = blockIdx.x * 256 + t;
    int v = (i < N_NODES) ? cnt[i] : 0;
    s[t] = v; __syncthreads();
    for (int off = 1; off < 256; off <<= 1) {
        int u = (t >= off) ? s[t - off] : 0;
        __syncthreads();
        s[t] += u;
        __syncthreads();
    }
    if (i < N_NODES) {
        int r = partial[blockIdx.x] + s[t] - v;
        rowp[i] = r;
        cur[i] = r;
        dinv[i] = rsqrtf(1.0f + (float)v);
    }
}

// scan_final for the src-CSR: counts are outdeg+1 (self entry), no dinv output
__global__ void scan_final2(const int* __restrict__ cnt, const int* __restrict__ partial,
                            int* __restrict__ rowp, int* __restrict__ cur) {
    __shared__ int s[256];
    int t = threadIdx.x;
    int i = blockIdx.x * 256 + t;
    int v = (i < N_NODES) ? cnt[i] + 1 : 0;
    s[t] = v; __syncthreads();
    for (int off = 1; off < 256; off <<= 1) {
        int u = (t >= off) ? s[t - off] : 0;
        __syncthreads();
        s[t] += u;
        __syncthreads();
    }
    if (i < N_NODES) {
        int r = partial[blockIdx.x] + s[t] - v;
        rowp[i] = r;
        cur[i] = r;
    }
}

// ---------------- scatter (R8 strided form) + src-CSR (graph,weight) scatter + split_x -------
// ep  : (src, w) grouped by dst   — for per-node aggregation (layers 1,2)
// ep2 : (graph(dst), w) grouped by src, plus self entries (batch[j], dinv_j^2)
//       — for the pooled-domain SPMM that replaces layer-3 aggregation
__global__ __launch_bounds__(256) void scatter_splitx(
        const int* __restrict__ src, const int* __restrict__ dst,
        const float* __restrict__ dinv, int* __restrict__ cur,
        int2* __restrict__ ep,
        const float* __restrict__ x, u16* __restrict__ x_bf,
        const int* __restrict__ bat, int* __restrict__ cur2,
        int2* __restrict__ ep2) {
    int bid = blockIdx.x;
    if (bid < CD_BLKS) {
        int base = bid * 1024 + threadIdx.x;
#pragma unroll
        for (int q = 0; q < 4; q++) {
            int e = base + q * 256;
            if (e < N_EDGES) {
                int d = dst[e];
                int s = src[e];
                float w = dinv[d] * dinv[s];
                int pos = atomicAdd(&cur[d], 1);
                int2 v; v.x = s; v.y = __float_as_int(w);
                ep[pos] = v;
                int g = bat[d];
                int pos2 = atomicAdd(&cur2[s], 1);
                int2 v2; v2.x = g; v2.y = __float_as_int(w);
                ep2[pos2] = v2;
            }
        }
        return;
    }
    bid -= CD_BLKS;
    if (bid < SPX_BLKS) {   // split_x: 4 floats/thread, 12500 blocks
        int idx = bid * 256 + threadIdx.x;
        float4 f = *(const float4*)&x[(size_t)idx * 4];
        ushort4 o;
        o.x = f2bf(f.x); o.y = f2bf(f.y); o.z = f2bf(f.z); o.w = f2bf(f.w);
        *(ushort4*)&x_bf[(size_t)idx * 4] = o;
        return;
    }
    bid -= SPX_BLKS;
    {   // self-loop entries for the pooled SPMM
        int base = bid * 1024 + threadIdx.x;
#pragma unroll
        for (int q = 0; q < 4; q++) {
            int j = base + q * 256;
            if (j < N_NODES) {
                float dv = dinv[j];
                int pos = atomicAdd(&cur2[j], 1);
                int2 v; v.x = bat[j]; v.y = __float_as_int(dv * dv);
                ep2[pos] = v;
            }
        }
    }
}

// ---------------- aggregation: half-wave (32 lanes x ushort8) per node, H=256 ----------------
__global__ __launch_bounds__(256) void gcn_agg256(
        const u16* __restrict__ in, const int* __restrict__ rowp,
        const int2* __restrict__ ep, const float* __restrict__ dinv,
        u16* __restrict__ outp) {
    int node = blockIdx.x * 8 + (threadIdx.x >> 5);
    int l = threadIdx.x & 31;
    int beg = rowp[node], end = rowp[node + 1];
    float a[8] = {};
    int e = beg;
    int2 pr[8];
    bool have = (e + 8 <= end);
    if (have) {
#pragma unroll
        for (int q = 0; q < 8; q++) pr[q] = ep[e + q];
    }
    while (have) {
        int2 g8[8];
#pragma unroll
        for (int q = 0; q < 8; q++) g8[q] = pr[q];
        int en = e + 8;
        bool haven = (en + 8 <= end);
        if (haven) {
#pragma unroll
            for (int q = 0; q < 8; q++) pr[q] = ep[en + q];
        }
#pragma unroll
        for (int q = 0; q < 8; q++) {
            u16x8 u = *(const u16x8*)&in[(size_t)g8[q].x * H + l * 8];
            float wt = __int_as_float(g8[q].y);
#pragma unroll
            for (int r = 0; r < 8; r++) a[r] += bf2f(u[r]) * wt;
        }
        e = en; have = haven;
    }
    for (; e < end; e++) {
        int2 pe = ep[e];
        float wt = __int_as_float(pe.y);
        u16x8 u = *(const u16x8*)&in[(size_t)pe.x * H + l * 8];
#pragma unroll
        for (int r = 0; r < 8; r++) a[r] += bf2f(u[r]) * wt;
    }
    float di = dinv[node];
    u16x8 us = *(const u16x8*)&in[(size_t)node * H + l * 8];
    float dd = di * di;
    u16x8 o;
#pragma unroll
    for (int r = 0; r < 8; r++) o[r] = f2bf(a[r] + bf2f(us[r]) * dd);
    *(u16x8*)&outp[(size_t)node * H + l * 8] = o;
}

// ---------------- aggregation: quarter-wave (16 lanes x ushort8) per node, F=128 ----------------
__global__ __launch_bounds__(256) void gcn_agg128(
        const u16* __restrict__ in, const int* __restrict__ rowp,
        const int2* __restrict__ ep, const float* __restrict__ dinv,
        u16* __restrict__ outp) {
    int node = blockIdx.x * 16 + (threadIdx.x >> 4);
    int l = threadIdx.x & 15;
    int beg = rowp[node], end = rowp[node + 1];
    float a[8] = {};
    int e = beg;
    int2 pr[8];
    bool have = (e + 8 <= end);
    if (have) {
#pragma unroll
        for (int q = 0; q < 8; q++) pr[q] = ep[e + q];
    }
    while (have) {
        int2 g8[8];
#pragma unroll
        for (int q = 0; q < 8; q++) g8[q] = pr[q];
        int en = e + 8;
        bool haven = (en + 8 <= end);
        if (haven) {
#pragma unroll
            for (int q = 0; q < 8; q++) pr[q] = ep[en + q];
        }
#pragma unroll
        for (int q = 0; q < 8; q++) {
            u16x8 u = *(const u16x8*)&in[(size_t)g8[q].x * F_IN + l * 8];
            float wt = __int_as_float(g8[q].y);
#pragma unroll
            for (int r = 0; r < 8; r++) a[r] += bf2f(u[r]) * wt;
        }
        e = en; have = haven;
    }
    for (; e < end; e++) {
        int2 pe = ep[e];
        float wt = __int_as_float(pe.y);
        u16x8 u = *(const u16x8*)&in[(size_t)pe.x * F_IN + l * 8];
#pragma unroll
        for (int r = 0; r < 8; r++) a[r] += bf2f(u[r]) * wt;
    }
    float di = dinv[node];
    u16x8 us = *(const u16x8*)&in[(size_t)node * F_IN + l * 8];
    float dd = di * di;
    u16x8 o;
#pragma unroll
    for (int r = 0; r < 8; r++) o[r] = f2bf(a[r] + bf2f(us[r]) * dd);
    *(u16x8*)&outp[(size_t)node * F_IN + l * 8] = o;
}

// ---------------- pooled-domain SPMM: pooled += U * H, streaming H src-major ----------------
// Replaces layer-3 aggregation + pool: pooled_g = sum_e[batch[dst]=g] w_e*h_src + self terms.
// Block = 1 column of grid: 2 graph-halves x 128 node-chunks; LDS holds 128 graphs x 256 cols f32.
// Wave (64 lanes) owns one node: lane l covers cols [4l,4l+4). ds_add swizzle ((i+(l>>3))&3)
// keeps bank aliasing at 2-way (free per m136).
#define CH_NODES 782   // ceil(N_NODES/128)
__global__ __launch_bounds__(1024) void pool_spmm(
        const u16* __restrict__ h, const int* __restrict__ rowp2,
        const int2* __restrict__ ep2, float* __restrict__ part) {
    __shared__ float sp[128 * 256];
    const int tid = threadIdx.x;
    {
        float4 z = {0.f, 0.f, 0.f, 0.f};
        for (int k = tid; k < 128 * 64; k += 1024) *(float4*)&sp[k * 4] = z;
    }
    __syncthreads();
    const int half = blockIdx.x >> 7;
    const int chunk = blockIdx.x & 127;
    const int g0 = half << 7;
    const int l = tid & 63;
    const int wv = tid >> 6;
    const int lb = l << 2;
    const int lsh = (l >> 3) & 3;
    int n0 = chunk * CH_NODES;
    int n1 = n0 + CH_NODES; if (n1 > N_NODES) n1 = N_NODES;
    for (int j = n0 + wv; j < n1; j += 16) {
        ushort4 rv = *(const ushort4*)&h[(size_t)j * H + lb];
        float f0 = bf2f(rv.x), f1 = bf2f(rv.y), f2 = bf2f(rv.z), f3 = bf2f(rv.w);
        int beg = rowp2[j], end = rowp2[j + 1];
        int e = beg;
        int2 pr[8];
        bool have = (e + 8 <= end);
        if (have) {
#pragma unroll
            for (int q = 0; q < 8; q++) pr[q] = ep2[e + q];
        }
        while (have) {
            int2 g8[8];
#pragma unroll
            for (int q = 0; q < 8; q++) g8[q] = pr[q];
            int en = e + 8;
            bool haven = (en + 8 <= end);
            if (haven) {
#pragma unroll
                for (int q = 0; q < 8; q++) pr[q] = ep2[en + q];
            }
#pragma unroll
            for (int q = 0; q < 8; q++) {
                int g = g8[q].x - g0;
                if ((unsigned)g < 128u) {
                    float wt = __int_as_float(g8[q].y);
                    float* row = &sp[g << 8];
                    atomicAdd(&row[lb + ((0 + lsh) & 3)], wt * f0);
                    atomicAdd(&row[lb + ((1 + lsh) & 3)], wt * f1);
                    atomicAdd(&row[lb + ((2 + lsh) & 3)], wt * f2);
                    atomicAdd(&row[lb + ((3 + lsh) & 3)], wt * f3);
                }
            }
            e = en; have = haven;
        }
        for (; e < end; e++) {
            int2 pe = ep2[e];
            int g = pe.x - g0;
            if ((unsigned)g < 128u) {
                float wt = __int_as_float(pe.y);
                float* row = &sp[g << 8];
                atomicAdd(&row[lb + ((0 + lsh) & 3)], wt * f0);
                atomicAdd(&row[lb + ((1 + lsh) & 3)], wt * f1);
                atomicAdd(&row[lb + ((2 + lsh) & 3)], wt * f2);
                atomicAdd(&row[lb + ((3 + lsh) & 3)], wt * f3);
            }
        }
    }
    __syncthreads();
    // writeback, undoing the col swizzle: slot p at sub-lane lp holds true col (lp*4 + (p-lsh)&3)
    float* pb = part + (size_t)blockIdx.x * (128 * 256);
    for (int k = tid; k < 128 * 256; k += 1024) {
        int cS = k & 255;
        int lp = cS >> 2, pp = cS & 3;
        int i = (pp - ((lp >> 3) & 3)) & 3;
        pb[(k & ~255) | ((lp << 2) + i)] = sp[k];
    }
}

// ---------------- pool finalize: reduce 128 chunk partials, divide by counts, hi/lo split ----
__global__ __launch_bounds__(256) void pool_finalize(
        const float* __restrict__ part, const int* __restrict__ goff,
        u16* __restrict__ phi, u16* __restrict__ plo) {
    int g = blockIdx.x, t = threadIdx.x;
    int gl = g & 127;
    const float* p0 = part + (size_t)(g >> 7) * 128 * 32768 + (size_t)gl * 256 + t;
    float a0 = 0.f, a1 = 0.f, a2 = 0.f, a3 = 0.f;
    for (int b = 0; b < 128; b += 4) {
        a0 += p0[(size_t)b * 32768];
        a1 += p0[(size_t)(b + 1) * 32768];
        a2 += p0[(size_t)(b + 2) * 32768];
        a3 += p0[(size_t)(b + 3) * 32768];
    }
    float acc = (a0 + a1) + (a2 + a3);
    float c = (float)(goff[g + 1] - goff[g]);
    acc /= fmaxf(c, 1.f);
    u16 hv = f2bf(acc);
    phi[g * H + t] = hv;
    plo[g * H + t] = f2bf(acc - bf2f(hv));
}

// ---------------- MFMA GEMM with bias(+relu) epilogue (node layers) ----------------
template<int K, bool RELU>
__global__ __launch_bounds__(256) void gemm_bias(
        const u16* __restrict__ A,
        const u16* __restrict__ Bhi, const u16* __restrict__ Blo,
        const float* __restrict__ bias, u16* __restrict__ C, int M) {
    __shared__ __align__(16) u16 sA[128 * 40];
    __shared__ __align__(16) u16 sB[2 * 128 * 40];
    const int tid = threadIdx.x;
    const int w = tid >> 6, l = tid & 63;
    const int wm = (w & 1) * 64, wn = (w >> 1) * 64;
    const int bm = blockIdx.x * 128, bn = blockIdx.y * 128;
    const int srow = tid >> 2;
    const int schunk = (tid & 3) * 8;
    const int lr = l & 15, lg = (l >> 4) * 8;

    f32x4 acc[4][4] = {};

    for (int k0 = 0; k0 < K; k0 += 32) {
        {
            int r0 = bm + srow, r1 = bm + srow + 64;
            u16x8 v0 = {}, v1 = {};
            if (r0 < M) v0 = *(const u16x8*)&A[(size_t)r0 * K + k0 + schunk];
            if (r1 < M) v1 = *(const u16x8*)&A[(size_t)r1 * K + k0 + schunk];
            *(u16x8*)&sA[srow * 40 + schunk] = v0;
            *(u16x8*)&sA[(srow + 64) * 40 + schunk] = v1;
        }
        {
            int n0 = bn + srow, n1 = bn + srow + 64;
            *(u16x8*)&sB[srow * 40 + schunk] = *(const u16x8*)&Bhi[(size_t)n0 * K + k0 + schunk];
            *(u16x8*)&sB[(srow + 64) * 40 + schunk] = *(const u16x8*)&Bhi[(size_t)n1 * K + k0 + schunk];
            *(u16x8*)&sB[128 * 40 + srow * 40 + schunk] = *(const u16x8*)&Blo[(size_t)n0 * K + k0 + schunk];
            *(u16x8*)&sB[128 * 40 + (srow + 64) * 40 + schunk] = *(const u16x8*)&Blo[(size_t)n1 * K + k0 + schunk];
        }
        __syncthreads();

        s16x8 af[4], bh[4], bl[4];
#pragma unroll
        for (int i = 0; i < 4; i++)
            af[i] = __builtin_bit_cast(s16x8, *(const u16x8*)&sA[(wm + i * 16 + lr) * 40 + lg]);
#pragma unroll
        for (int j = 0; j < 4; j++) {
            bh[j] = __builtin_bit_cast(s16x8, *(const u16x8*)&sB[(wn + j * 16 + lr) * 40 + lg]);
            bl[j] = __builtin_bit_cast(s16x8, *(const u16x8*)&sB[128 * 40 + (wn + j * 16 + lr) * 40 + lg]);
        }
#pragma unroll
        for (int i = 0; i < 4; i++) {
#pragma unroll
            for (int j = 0; j < 4; j++) {
                acc[i][j] = __builtin_amdgcn_mfma_f32_16x16x32_bf16(af[i], bh[j], acc[i][j], 0, 0, 0);
                acc[i][j] = __builtin_amdgcn_mfma_f32_16x16x32_bf16(af[i], bl[j], acc[i][j], 0, 0, 0);
            }
        }
        __syncthreads();
    }

    float bcol[4];
#pragma unroll
    for (int j = 0; j < 4; j++) bcol[j] = bias[bn + wn + j * 16 + lr];

    const int lq = (l >> 4) * 4;
#pragma unroll
    for (int i = 0; i < 4; i++) {
#pragma unroll
        for (int r0 = 0; r0 < 4; r0++) {
            int row = bm + wm + i * 16 + lq + r0;
            if (row < M) {
#pragma unroll
                for (int j = 0; j < 4; j++) {
                    float v = acc[i][j][r0] + bcol[j];
                    if (RELU) v = fmaxf(v, 0.f);
                    C[(size_t)row * H + bn + wn + j * 16 + lr] = f2bf(v);
                }
            }
        }
    }
}

// ---------------- split-precision MFMA GEMM (MLP tail) ----------------
template<int K, int NW, bool RELU, bool F32OUT>
__global__ __launch_bounds__(256) void gemm_split(
        const u16* __restrict__ Ahi, const u16* __restrict__ Alo,
        const u16* __restrict__ Bhi, const u16* __restrict__ Blo,
        const float* __restrict__ bias,
        u16* __restrict__ Chi, u16* __restrict__ Clo, float* __restrict__ Cf,
        int M) {
    __shared__ __align__(16) u16 sA[2 * 128 * 40];
    __shared__ __align__(16) u16 sB[2 * 128 * 40];
    const int tid = threadIdx.x;
    const int w = tid >> 6, l = tid & 63;
    const int wm = (w & 1) * 64, wn = (w >> 1) * 64;
    const int bm = blockIdx.x * 128, bn = blockIdx.y * 128;
    const int srow = tid >> 2;
    const int schunk = (tid & 3) * 8;
    const int lr = l & 15, lg = (l >> 4) * 8;

    f32x4 acc[4][4] = {};

    for (int k0 = 0; k0 < K; k0 += 32) {
        {
            int r0 = bm + srow, r1 = bm + srow + 64;
            u16x8 v0 = {}, v1 = {}, w0 = {}, w1 = {};
            if (r0 < M) {
                v0 = *(const u16x8*)&Ahi[(size_t)r0 * K + k0 + schunk];
                w0 = *(const u16x8*)&Alo[(size_t)r0 * K + k0 + schunk];
            }
            if (r1 < M) {
                v1 = *(const u16x8*)&Ahi[(size_t)r1 * K + k0 + schunk];
                w1 = *(const u16x8*)&Alo[(size_t)r1 * K + k0 + schunk];
            }
            *(u16x8*)&sA[srow * 40 + schunk] = v0;
            *(u16x8*)&sA[(srow + 64) * 40 + schunk] = v1;
            *(u16x8*)&sA[128 * 40 + srow * 40 + schunk] = w0;
            *(u16x8*)&sA[128 * 40 + (srow + 64) * 40 + schunk] = w1;
        }
        {
            int n0 = bn + srow, n1 = bn + srow + 64;
            *(u16x8*)&sB[srow * 40 + schunk] = *(const u16x8*)&Bhi[(size_t)n0 * K + k0 + schunk];
            *(u16x8*)&sB[(srow + 64) * 40 + schunk] = *(const u16x8*)&Bhi[(size_t)n1 * K + k0 + schunk];
            *(u16x8*)&sB[128 * 40 + srow * 40 + schunk] = *(const u16x8*)&Blo[(size_t)n0 * K + k0 + schunk];
            *(u16x8*)&sB[128 * 40 + (srow + 64) * 40 + schunk] = *(const u16x8*)&Blo[(size_t)n1 * K + k0 + schunk];
        }
        __syncthreads();

        s16x8 af[4], al[4], bh[4], bl[4];
#pragma unroll
        for (int i = 0; i < 4; i++) {
            af[i] = __builtin_bit_cast(s16x8, *(const u16x8*)&sA[(wm + i * 16 + lr) * 40 + lg]);
            al[i] = __builtin_bit_cast(s16x8, *(const u16x8*)&sA[128 * 40 + (wm + i * 16 + lr) * 40 + lg]);
        }
#pragma unroll
        for (int j = 0; j < 4; j++) {
            bh[j] = __builtin_bit_cast(s16x8, *(const u16x8*)&sB[(wn + j * 16 + lr) * 40 + lg]);
            bl[j] = __builtin_bit_cast(s16x8, *(const u16x8*)&sB[128 * 40 + (wn + j * 16 + lr) * 40 + lg]);
        }
#pragma unroll
        for (int i = 0; i < 4; i++) {
#pragma unroll
            for (int j = 0; j < 4; j++) {
                acc[i][j] = __builtin_amdgcn_mfma_f32_16x16x32_bf16(af[i], bh[j], acc[i][j], 0, 0, 0);
                acc[i][j] = __builtin_amdgcn_mfma_f32_16x16x32_bf16(af[i], bl[j], acc[i][j], 0, 0, 0);
                acc[i][j] = __builtin_amdgcn_mfma_f32_16x16x32_bf16(al[i], bh[j], acc[i][j], 0, 0, 0);
            }
        }
        __syncthreads();
    }

    float bcol[4];
#pragma unroll
    for (int j = 0; j < 4; j++) bcol[j] = bias[bn + wn + j * 16 + lr];

    const int lq = (l >> 4) * 4;
#pragma unroll
    for (int i = 0; i < 4; i++) {
#pragma unroll
        for (int r0 = 0; r0 < 4; r0++) {
            int row = bm + wm + i * 16 + lq + r0;
            if (row < M) {
#pragma unroll
                for (int j = 0; j < 4; j++) {
                    float v = acc[i][j][r0] + bcol[j];
                    if (RELU) v = fmaxf(v, 0.f);
                    size_t idx = (size_t)row * NW + bn + wn + j * 16 + lr;
                    if (F32OUT) {
                        Cf[idx] = v;
                    } else {
                        u16 hv = f2bf(v);
                        Chi[idx] = hv;
                        Clo[idx] = f2bf(v - bf2f(hv));
                    }
                }
            }
        }
    }
}

// ---------------- launch ----------------
extern "C" void kernel_launch(void* const* d_in, const int* in_sizes, int n_in,
                              void* d_out, int out_size, void* d_ws, size_t ws_size,
                              hipStream_t stream) {
    const float* x   = (const float*)d_in[0];
    const int*   src = (const int*)d_in[1];
    const int*   dst = (const int*)d_in[2];
    const int*   bat = (const int*)d_in[3];
    const float* W1  = (const float*)d_in[4];  const float* b1  = (const float*)d_in[5];
    const float* W2  = (const float*)d_in[6];  const float* b2  = (const float*)d_in[7];
    const float* W3  = (const float*)d_in[8];  const float* b3  = (const float*)d_in[9];
    const float* Wm1 = (const float*)d_in[10]; const float* bm1 = (const float*)d_in[11];
    const float* Wm2 = (const float*)d_in[12]; const float* bm2 = (const float*)d_in[13];
    float* out = (float*)d_out;

    char* p = (char*)d_ws;
    auto carve = [&](size_t bytes) -> void* {
        void* r = (void*)p;
        p += (bytes + 511) & ~(size_t)511;
        return r;
    };
    u16*   x_bf    = (u16*)  carve((size_t)N_NODES * F_IN * 2);
    u16*   aggX    = (u16*)  carve((size_t)N_NODES * F_IN * 2);
    u16*   bufA    = (u16*)  carve((size_t)N_NODES * H * 2);
    u16*   bufB    = (u16*)  carve((size_t)N_NODES * H * 2);
    float* dinv    = (float*)carve((size_t)N_NODES * 4);
    int*   degc    = (int*)  carve((size_t)N_NODES * 4);
    int*   rowp    = (int*)  carve((size_t)(N_NODES + 1) * 4);
    int*   cur     = (int*)  carve((size_t)N_NODES * 4);
    int2*  ep      = (int2*) carve((size_t)N_EDGES * 8);
    int*   partial = (int*)  carve(4096);
    int*   goff    = (int*)  carve((size_t)(G_GR + 1) * 4);
    u16*   Wt1_hi  = (u16*)  carve((size_t)F_IN * H * 2);
    u16*   Wt1_lo  = (u16*)  carve((size_t)F_IN * H * 2);
    u16*   Wt2_hi  = (u16*)  carve((size_t)H * H * 2);
    u16*   Wt2_lo  = (u16*)  carve((size_t)H * H * 2);
    u16*   Wt3_hi  = (u16*)  carve((size_t)H * H * 2);
    u16*   Wt3_lo  = (u16*)  carve((size_t)H * H * 2);
    u16*   Wm1t_hi = (u16*)  carve((size_t)H * NHID * 2);
    u16*   Wm1t_lo = (u16*)  carve((size_t)H * NHID * 2);
    u16*   Wm2t_hi = (u16*)  carve((size_t)NHID * NOUT * 2);
    u16*   Wm2t_lo = (u16*)  carve((size_t)NHID * NOUT * 2);
    u16*   p_hi    = (u16*)  carve((size_t)G_GR * H * 2);
    u16*   p_lo    = (u16*)  carve((size_t)G_GR * H * 2);
    u16*   y_hi    = (u16*)  carve((size_t)G_GR * H * 2);
    u16*   y_lo    = (u16*)  carve((size_t)G_GR * H * 2);
    u16*   hd_hi   = (u16*)  carve((size_t)G_GR * NHID * 2);
    u16*   hd_lo   = (u16*)  carve((size_t)G_GR * NHID * 2);
    // src-CSR for the pooled-domain SPMM (layer 3)
    int*   srcc    = (int*)  carve((size_t)N_NODES * 4);
    int*   rowp2   = (int*)  carve((size_t)(N_NODES + 1) * 4);
    int*   cur2    = (int*)  carve((size_t)N_NODES * 4);
    int*   partial2= (int*)  carve(4096);
    int2*  ep2     = (int2*) carve((size_t)(N_EDGES + N_NODES) * 8);
    float* spart   = (float*)bufB;   // bufB is dead on the new path; 256 blocks x 128KB = 32MB <= 51.2MB

    const int NB = (N_NODES + 255) / 256;

    hipMemsetAsync(degc, 0, (size_t)N_NODES * 4, stream);
    hipMemsetAsync(srcc, 0, (size_t)N_NODES * 4, stream);
    prep_head<<<HEAD_BLKS, 256, 0, stream>>>(src, dst, degc, srcc,
                                             W1, Wt1_hi, Wt1_lo,
                                             W2, Wt2_hi, Wt2_lo,
                                             W3, Wt3_hi, Wt3_lo,
                                             Wm1, Wm1t_hi, Wm1t_lo,
                                             Wm2, Wm2t_hi, Wm2t_lo, bat, goff);
    scan_partial<<<NB, 256, 0, stream>>>(degc, partial, 0);
    scan_partial<<<NB, 256, 0, stream>>>(srcc, partial2, 1);     // +1 self entry per node
    scan_offsets<<<1, 512, 0, stream>>>(partial, NB, rowp, N_EDGES);
    scan_offsets<<<1, 512, 0, stream>>>(partial2, NB, rowp2, N_EDGES + N_NODES);
    scan_final_dinv<<<NB, 256, 0, stream>>>(degc, partial, rowp, cur, dinv);
    scan_final2<<<NB, 256, 0, stream>>>(srcc, partial2, rowp2, cur2);
    // scatter (dst-CSR ep + src-CSR ep2 + self entries) + split_x freight
    scatter_splitx<<<CD_BLKS + SPX_BLKS + SELF_BLKS, 256, 0, stream>>>(
        src, dst, dinv, cur, ep, x, x_bf, bat, cur2, ep2);

    dim3 ggrid((N_NODES + 127) / 128, 2);

    // layer 1: aggregate-first (256B rows), then transform+bias+relu
    gcn_agg128<<<N_NODES / 16, 256, 0, stream>>>(x_bf, rowp, ep, dinv, aggX);
    gemm_bias<F_IN, true><<<ggrid, 256, 0, stream>>>(aggX, Wt1_hi, Wt1_lo, b1, bufA, N_NODES);
    // layer 2
    gcn_agg256<<<N_NODES / 8, 256, 0, stream>>>(bufA, rowp, ep, dinv, bufB);
    gemm_bias<H, true><<<ggrid, 256, 0, stream>>>(bufB, Wt2_hi, Wt2_lo, b2, bufA, N_NODES);
    // layer 3 + pool, fused in pooled domain: pooled = U * bufA (src-major stream, LDS accum)
    pool_spmm<<<256, 1024, 0, stream>>>(bufA, rowp2, ep2, spart);
    pool_finalize<<<G_GR, 256, 0, stream>>>(spart, goff, p_hi, p_lo);

    // tail: y=pW3+b3 -> hidden=relu(yWm1+bm1) -> out=hidden Wm2+bm2
    dim3 g3(2, 2), gm1(2, 4), gm2(2, 2);
    gemm_split<H, H, false, false><<<g3, 256, 0, stream>>>(
        p_hi, p_lo, Wt3_hi, Wt3_lo, b3, y_hi, y_lo, nullptr, G_GR);
    gemm_split<H, NHID, true, false><<<gm1, 256, 0, stream>>>(
        y_hi, y_lo, Wm1t_hi, Wm1t_lo, bm1, hd_hi, hd_lo, nullptr, G_GR);
    gemm_split<NHID, NOUT, false, true><<<gm2, 256, 0, stream>>>(
        hd_hi, hd_lo, Wm2t_hi, Wm2t_lo, bm2, nullptr, nullptr, out, G_GR);
}

// Round 2
// 724.390 us; speedup vs baseline: 4.3379x; 4.3379x over previous
//
#include <hip/hip_runtime.h>
#include <hip/hip_bf16.h>

#define N_NODES 100000
#define N_EDGES 1600000
#define F_IN    128
#define H       256
#define NHID    512
#define NOUT    256
#define G_GR    256

typedef unsigned short u16;
typedef __attribute__((ext_vector_type(8))) short s16x8;
typedef __attribute__((ext_vector_type(8))) unsigned short u16x8;
typedef __attribute__((ext_vector_type(4))) float f32x4;

__device__ __forceinline__ float bf2f(u16 u) {
    union { unsigned int i; float f; } v; v.i = ((unsigned int)u) << 16; return v.f;
}
__device__ __forceinline__ u16 f2bf(float f) {
    union { float f; unsigned int i; } v; v.f = f;
    unsigned int x = v.i;
    x += 0x7fffu + ((x >> 16) & 1u);
    return (u16)(x >> 16);
}

// ---------------- head: count_deg (atomics, R8 strided form) + weight transposes + goff -----
#define CD_BLKS   1563                        // 4 strided edges/thread (R8 known-good form)
#define SPX_BLKS  ((N_NODES * F_IN) / 1024)   // 12500 — carried by scatter kernel
#define T1_BLKS   ((F_IN * H) / 256)
#define T2_BLKS   ((H * H) / 256)
#define T3_BLKS   ((H * H) / 256)
#define TM1_BLKS  ((H * NHID) / 256)
#define TM2_BLKS  ((NHID * NOUT) / 256)
#define HEAD_BLKS (CD_BLKS + T1_BLKS + T2_BLKS + T3_BLKS + TM1_BLKS + TM2_BLKS + 2)

__device__ __forceinline__ void transpose_split_body(const float* __restrict__ W,
        u16* __restrict__ thi, u16* __restrict__ tlo, int K, int N, int id) {
    int n = id / K, k = id - n * K;
    float f = W[(size_t)k * N + n];
    u16 h = f2bf(f);
    thi[id] = h;
    tlo[id] = f2bf(f - bf2f(h));
}

__global__ __launch_bounds__(256) void prep_head(
        const int* __restrict__ dst, int* __restrict__ degc,
        const float* __restrict__ W1, u16* __restrict__ t1h, u16* __restrict__ t1l,
        const float* __restrict__ W2, u16* __restrict__ t2h, u16* __restrict__ t2l,
        const float* __restrict__ W3, u16* __restrict__ t3h, u16* __restrict__ t3l,
        const float* __restrict__ Wm1, u16* __restrict__ tm1h, u16* __restrict__ tm1l,
        const float* __restrict__ Wm2, u16* __restrict__ tm2h, u16* __restrict__ tm2l,
        const int* __restrict__ batch, int* __restrict__ goff) {
    int bid = blockIdx.x;
    if (bid < CD_BLKS) {
        int base = bid * 1024 + threadIdx.x;
#pragma unroll
        for (int q = 0; q < 4; q++) {
            int e = base + q * 256;
            if (e < N_EDGES) atomicAdd(&degc[dst[e]], 1);
        }
        return;
    }
    bid -= CD_BLKS;
    if (bid < T1_BLKS) {
        transpose_split_body(W1, t1h, t1l, F_IN, H, bid * 256 + threadIdx.x);
        return;
    }
    bid -= T1_BLKS;
    if (bid < T2_BLKS) {
        transpose_split_body(W2, t2h, t2l, H, H, bid * 256 + threadIdx.x);
        return;
    }
    bid -= T2_BLKS;
    if (bid < T3_BLKS) {
        transpose_split_body(W3, t3h, t3l, H, H, bid * 256 + threadIdx.x);
        return;
    }
    bid -= T3_BLKS;
    if (bid < TM1_BLKS) {
        transpose_split_body(Wm1, tm1h, tm1l, H, NHID, bid * 256 + threadIdx.x);
        return;
    }
    bid -= TM1_BLKS;
    if (bid < TM2_BLKS) {
        transpose_split_body(Wm2, tm2h, tm2l, NHID, NOUT, bid * 256 + threadIdx.x);
        return;
    }
    bid -= TM2_BLKS;
    {
        int g = bid * 256 + threadIdx.x;
        if (g > G_GR) return;
        int lo = 0, hi = N_NODES;
        while (lo < hi) {
            int mid = (lo + hi) >> 1;
            if (batch[mid] < g) lo = mid + 1; else hi = mid;
        }
        goff[g] = lo;
    }
}

// ---------------- scan (CSR rowp) ----------------
__global__ void scan_partial(const int* __restrict__ cnt, int* __restrict__ partial) {
    __shared__ int s[256];
    int t = threadIdx.x;
    int i = blockIdx.x * 256 + t;
    int v = (i < N_NODES) ? cnt[i] : 0;
    s[t] = v; __syncthreads();
    for (int off = 128; off > 0; off >>= 1) {
        if (t < off) s[t] += s[t + off];
        __syncthreads();
    }
    if (t == 0) partial[blockIdx.x] = s[0];
}

__global__ void scan_offsets(int* __restrict__ partial, int nb, int* __restrict__ rowp) {
    __shared__ int s[512];
    int t = threadIdx.x;
    int orig = (t < nb) ? partial[t] : 0;
    s[t] = orig; __syncthreads();
    for (int off = 1; off < 512; off <<= 1) {
        int u = (t >= off) ? s[t - off] : 0;
        __syncthreads();
        s[t] += u;
        __syncthreads();
    }
    if (t < nb) partial[t] = s[t] - orig;
    if (t == 0) rowp[N_NODES] = N_EDGES;
}

__global__ void scan_final_dinv(const int* __restrict__ cnt, const int* __restrict__ partial,
                                int* __restrict__ rowp, int* __restrict__ cur,
                                float* __restrict__ dinv) {
    __shared__ int s[256];
    int t = threadIdx.x;
    int i = blockIdx.x * 256 + t;
    int v = (i < N_NODES) ? cnt[i] : 0;
    s[t] = v; __syncthreads();
    for (int off = 1; off < 256; off <<= 1) {
        int u = (t >= off) ? s[t - off] : 0;
        __syncthreads();
        s[t] += u;
        __syncthreads();
    }
    if (i < N_NODES) {
        int r = partial[blockIdx.x] + s[t] - v;
        rowp[i] = r;
        cur[i] = r;
        dinv[i] = rsqrtf(1.0f + (float)v);
    }
}

// ---------------- scatter (R8 strided form) + split_x streaming freight ----------------
__global__ __launch_bounds__(256) void scatter_splitx(
        const int* __restrict__ src, const int* __restrict__ dst,
        const float* __restrict__ dinv, int* __restrict__ cur,
        int2* __restrict__ ep,
        const float* __restrict__ x, u16* __restrict__ x_bf) {
    int bid = blockIdx.x;
    if (bid < CD_BLKS) {
        int base = bid * 1024 + threadIdx.x;
#pragma unroll
        for (int q = 0; q < 4; q++) {
            int e = base + q * 256;
            if (e < N_EDGES) {
                int d = dst[e];
                int s = src[e];
                float w = dinv[d] * dinv[s];
                int pos = atomicAdd(&cur[d], 1);
                int2 v; v.x = s; v.y = __float_as_int(w);
                ep[pos] = v;
            }
        }
        return;
    }
    bid -= CD_BLKS;
    {   // split_x: 4 floats/thread, 12500 blocks
        int idx = bid * 256 + threadIdx.x;
        float4 f = *(const float4*)&x[(size_t)idx * 4];
        ushort4 o;
        o.x = f2bf(f.x); o.y = f2bf(f.y); o.z = f2bf(f.z); o.w = f2bf(f.w);
        *(ushort4*)&x_bf[(size_t)idx * 4] = o;
    }
}

// ---------------- aggregation: half-wave (32 lanes x ushort8) per node, H=256 ----------------
__global__ __launch_bounds__(256) void gcn_agg256(
        const u16* __restrict__ in, const int* __restrict__ rowp,
        const int2* __restrict__ ep, const float* __restrict__ dinv,
        u16* __restrict__ outp) {
    int node = blockIdx.x * 8 + (threadIdx.x >> 5);
    int l = threadIdx.x & 31;
    int beg = rowp[node], end = rowp[node + 1];
    float a[8] = {};
    int e = beg;
    int2 pr[8];
    bool have = (e + 8 <= end);
    if (have) {
#pragma unroll
        for (int q = 0; q < 8; q++) pr[q] = ep[e + q];
    }
    while (have) {
        int2 g8[8];
#pragma unroll
        for (int q = 0; q < 8; q++) g8[q] = pr[q];
        int en = e + 8;
        bool haven = (en + 8 <= end);
        if (haven) {
#pragma unroll
            for (int q = 0; q < 8; q++) pr[q] = ep[en + q];
        }
#pragma unroll
        for (int q = 0; q < 8; q++) {
            u16x8 u = *(const u16x8*)&in[(size_t)g8[q].x * H + l * 8];
            float wt = __int_as_float(g8[q].y);
#pragma unroll
            for (int r = 0; r < 8; r++) a[r] += bf2f(u[r]) * wt;
        }
        e = en; have = haven;
    }
    for (; e < end; e++) {
        int2 pe = ep[e];
        float wt = __int_as_float(pe.y);
        u16x8 u = *(const u16x8*)&in[(size_t)pe.x * H + l * 8];
#pragma unroll
        for (int r = 0; r < 8; r++) a[r] += bf2f(u[r]) * wt;
    }
    float di = dinv[node];
    u16x8 us = *(const u16x8*)&in[(size_t)node * H + l * 8];
    float dd = di * di;
    u16x8 o;
#pragma unroll
    for (int r = 0; r < 8; r++) o[r] = f2bf(a[r] + bf2f(us[r]) * dd);
    *(u16x8*)&outp[(size_t)node * H + l * 8] = o;
}

// ---------------- aggregation: quarter-wave (16 lanes x ushort8) per node, F=128 ----------------
__global__ __launch_bounds__(256) void gcn_agg128(
        const u16* __restrict__ in, const int* __restrict__ rowp,
        const int2* __restrict__ ep, const float* __restrict__ dinv,
        u16* __restrict__ outp) {
    int node = blockIdx.x * 16 + (threadIdx.x >> 4);
    int l = threadIdx.x & 15;
    int beg = rowp[node], end = rowp[node + 1];
    float a[8] = {};
    int e = beg;
    int2 pr[8];
    bool have = (e + 8 <= end);
    if (have) {
#pragma unroll
        for (int q = 0; q < 8; q++) pr[q] = ep[e + q];
    }
    while (have) {
        int2 g8[8];
#pragma unroll
        for (int q = 0; q < 8; q++) g8[q] = pr[q];
        int en = e + 8;
        bool haven = (en + 8 <= end);
        if (haven) {
#pragma unroll
            for (int q = 0; q < 8; q++) pr[q] = ep[en + q];
        }
#pragma unroll
        for (int q = 0; q < 8; q++) {
            u16x8 u = *(const u16x8*)&in[(size_t)g8[q].x * F_IN + l * 8];
            float wt = __int_as_float(g8[q].y);
#pragma unroll
            for (int r = 0; r < 8; r++) a[r] += bf2f(u[r]) * wt;
        }
        e = en; have = haven;
    }
    for (; e < end; e++) {
        int2 pe = ep[e];
        float wt = __int_as_float(pe.y);
        u16x8 u = *(const u16x8*)&in[(size_t)pe.x * F_IN + l * 8];
#pragma unroll
        for (int r = 0; r < 8; r++) a[r] += bf2f(u[r]) * wt;
    }
    float di = dinv[node];
    u16x8 us = *(const u16x8*)&in[(size_t)node * F_IN + l * 8];
    float dd = di * di;
    u16x8 o;
#pragma unroll
    for (int r = 0; r < 8; r++) o[r] = f2bf(a[r] + bf2f(us[r]) * dd);
    *(u16x8*)&outp[(size_t)node * F_IN + l * 8] = o;
}

// ---------------- layer-3 fused agg+pool: gather form, no per-node output ----------------
// Same gather as gcn_agg256, but the per-node f32 row goes to an LDS tile (plain writes),
// the block reduces its 8 nodes per graph slot (batch-sorted: usually 1, sometimes 2 graphs),
// and flushes 1-2 rows via global f32 atomicAdd into poolacc[G][H] (256 KB, L2-resident).
__global__ __launch_bounds__(256) void gcn_agg_pool(
        const u16* __restrict__ in, const int* __restrict__ rowp,
        const int2* __restrict__ ep, const float* __restrict__ dinv,
        const int* __restrict__ batch, float* __restrict__ poolacc) {
    __shared__ __align__(16) float pacc[8][H];
    __shared__ int gslot[8];
    const int tid = threadIdx.x;
    const int hw = tid >> 5;
    const int l = tid & 31;
    const int node = blockIdx.x * 8 + hw;
    const int gbase = batch[blockIdx.x * 8];

    int beg = rowp[node], end = rowp[node + 1];
    float a[8] = {};
    int e = beg;
    int2 pr[8];
    bool have = (e + 8 <= end);
    if (have) {
#pragma unroll
        for (int q = 0; q < 8; q++) pr[q] = ep[e + q];
    }
    while (have) {
        int2 g8[8];
#pragma unroll
        for (int q = 0; q < 8; q++) g8[q] = pr[q];
        int en = e + 8;
        bool haven = (en + 8 <= end);
        if (haven) {
#pragma unroll
            for (int q = 0; q < 8; q++) pr[q] = ep[en + q];
        }
#pragma unroll
        for (int q = 0; q < 8; q++) {
            u16x8 u = *(const u16x8*)&in[(size_t)g8[q].x * H + l * 8];
            float wt = __int_as_float(g8[q].y);
#pragma unroll
            for (int r = 0; r < 8; r++) a[r] += bf2f(u[r]) * wt;
        }
        e = en; have = haven;
    }
    for (; e < end; e++) {
        int2 pe = ep[e];
        float wt = __int_as_float(pe.y);
        u16x8 u = *(const u16x8*)&in[(size_t)pe.x * H + l * 8];
#pragma unroll
        for (int r = 0; r < 8; r++) a[r] += bf2f(u[r]) * wt;
    }
    float di = dinv[node];
    u16x8 us = *(const u16x8*)&in[(size_t)node * H + l * 8];
    float dd = di * di;
    f32x4 lo4, hi4;
#pragma unroll
    for (int r = 0; r < 4; r++) lo4[r] = a[r] + bf2f(us[r]) * dd;
#pragma unroll
    for (int r = 0; r < 4; r++) hi4[r] = a[r + 4] + bf2f(us[r + 4]) * dd;
    *(f32x4*)&pacc[hw][l * 8] = lo4;
    *(f32x4*)&pacc[hw][l * 8 + 4] = hi4;
    if (l == 0) gslot[hw] = batch[node] - gbase;
    __syncthreads();

    // reduce 8 node-rows by graph slot, flush with global f32 atomics
    int smax = gslot[7];          // batch sorted -> slots non-decreasing
    float v[8];
#pragma unroll
    for (int q = 0; q < 8; q++) v[q] = pacc[q][tid];
    for (int s = 0; s <= smax; s++) {
        float acc = 0.f;
#pragma unroll
        for (int q = 0; q < 8; q++)
            if (gslot[q] == s) acc += v[q];
        atomicAdd(&poolacc[(size_t)(gbase + s) * H + tid], acc);
    }
}

// ---------------- pool finalize: divide by counts, hi/lo bf16 split ----------------
__global__ __launch_bounds__(256) void pool_finalize2(
        const float* __restrict__ poolacc, const int* __restrict__ goff,
        u16* __restrict__ phi, u16* __restrict__ plo) {
    int g = blockIdx.x, t = threadIdx.x;
    float c = (float)(goff[g + 1] - goff[g]);
    float acc = poolacc[(size_t)g * H + t] / fmaxf(c, 1.f);
    u16 hv = f2bf(acc);
    phi[g * H + t] = hv;
    plo[g * H + t] = f2bf(acc - bf2f(hv));
}

// ---------------- MFMA GEMM with bias(+relu) epilogue (node layers) ----------------
template<int K, bool RELU>
__global__ __launch_bounds__(256) void gemm_bias(
        const u16* __restrict__ A,
        const u16* __restrict__ Bhi, const u16* __restrict__ Blo,
        const float* __restrict__ bias, u16* __restrict__ C, int M) {
    __shared__ __align__(16) u16 sA[128 * 40];
    __shared__ __align__(16) u16 sB[2 * 128 * 40];
    const int tid = threadIdx.x;
    const int w = tid >> 6, l = tid & 63;
    const int wm = (w & 1) * 64, wn = (w >> 1) * 64;
    const int bm = blockIdx.x * 128, bn = blockIdx.y * 128;
    const int srow = tid >> 2;
    const int schunk = (tid & 3) * 8;
    const int lr = l & 15, lg = (l >> 4) * 8;

    f32x4 acc[4][4] = {};

    for (int k0 = 0; k0 < K; k0 += 32) {
        {
            int r0 = bm + srow, r1 = bm + srow + 64;
            u16x8 v0 = {}, v1 = {};
            if (r0 < M) v0 = *(const u16x8*)&A[(size_t)r0 * K + k0 + schunk];
            if (r1 < M) v1 = *(const u16x8*)&A[(size_t)r1 * K + k0 + schunk];
            *(u16x8*)&sA[srow * 40 + schunk] = v0;
            *(u16x8*)&sA[(srow + 64) * 40 + schunk] = v1;
        }
        {
            int n0 = bn + srow, n1 = bn + srow + 64;
            *(u16x8*)&sB[srow * 40 + schunk] = *(const u16x8*)&Bhi[(size_t)n0 * K + k0 + schunk];
            *(u16x8*)&sB[(srow + 64) * 40 + schunk] = *(const u16x8*)&Bhi[(size_t)n1 * K + k0 + schunk];
            *(u16x8*)&sB[128 * 40 + srow * 40 + schunk] = *(const u16x8*)&Blo[(size_t)n0 * K + k0 + schunk];
            *(u16x8*)&sB[128 * 40 + (srow + 64) * 40 + schunk] = *(const u16x8*)&Blo[(size_t)n1 * K + k0 + schunk];
        }
        __syncthreads();

        s16x8 af[4], bh[4], bl[4];
#pragma unroll
        for (int i = 0; i < 4; i++)
            af[i] = __builtin_bit_cast(s16x8, *(const u16x8*)&sA[(wm + i * 16 + lr) * 40 + lg]);
#pragma unroll
        for (int j = 0; j < 4; j++) {
            bh[j] = __builtin_bit_cast(s16x8, *(const u16x8*)&sB[(wn + j * 16 + lr) * 40 + lg]);
            bl[j] = __builtin_bit_cast(s16x8, *(const u16x8*)&sB[128 * 40 + (wn + j * 16 + lr) * 40 + lg]);
        }
#pragma unroll
        for (int i = 0; i < 4; i++) {
#pragma unroll
            for (int j = 0; j < 4; j++) {
                acc[i][j] = __builtin_amdgcn_mfma_f32_16x16x32_bf16(af[i], bh[j], acc[i][j], 0, 0, 0);
                acc[i][j] = __builtin_amdgcn_mfma_f32_16x16x32_bf16(af[i], bl[j], acc[i][j], 0, 0, 0);
            }
        }
        __syncthreads();
    }

    float bcol[4];
#pragma unroll
    for (int j = 0; j < 4; j++) bcol[j] = bias[bn + wn + j * 16 + lr];

    const int lq = (l >> 4) * 4;
#pragma unroll
    for (int i = 0; i < 4; i++) {
#pragma unroll
        for (int r0 = 0; r0 < 4; r0++) {
            int row = bm + wm + i * 16 + lq + r0;
            if (row < M) {
#pragma unroll
                for (int j = 0; j < 4; j++) {
                    float v = acc[i][j][r0] + bcol[j];
                    if (RELU) v = fmaxf(v, 0.f);
                    C[(size_t)row * H + bn + wn + j * 16 + lr] = f2bf(v);
                }
            }
        }
    }
}

// ---------------- split-precision MFMA GEMM (MLP tail) ----------------
template<int K, int NW, bool RELU, bool F32OUT>
__global__ __launch_bounds__(256) void gemm_split(
        const u16* __restrict__ Ahi, const u16* __restrict__ Alo,
        const u16* __restrict__ Bhi, const u16* __restrict__ Blo,
        const float* __restrict__ bias,
        u16* __restrict__ Chi, u16* __restrict__ Clo, float* __restrict__ Cf,
        int M) {
    __shared__ __align__(16) u16 sA[2 * 128 * 40];
    __shared__ __align__(16) u16 sB[2 * 128 * 40];
    const int tid = threadIdx.x;
    const int w = tid >> 6, l = tid & 63;
    const int wm = (w & 1) * 64, wn = (w >> 1) * 64;
    const int bm = blockIdx.x * 128, bn = blockIdx.y * 128;
    const int srow = tid >> 2;
    const int schunk = (tid & 3) * 8;
    const int lr = l & 15, lg = (l >> 4) * 8;

    f32x4 acc[4][4] = {};

    for (int k0 = 0; k0 < K; k0 += 32) {
        {
            int r0 = bm + srow, r1 = bm + srow + 64;
            u16x8 v0 = {}, v1 = {}, w0 = {}, w1 = {};
            if (r0 < M) {
                v0 = *(const u16x8*)&Ahi[(size_t)r0 * K + k0 + schunk];
                w0 = *(const u16x8*)&Alo[(size_t)r0 * K + k0 + schunk];
            }
            if (r1 < M) {
                v1 = *(const u16x8*)&Ahi[(size_t)r1 * K + k0 + schunk];
                w1 = *(const u16x8*)&Alo[(size_t)r1 * K + k0 + schunk];
            }
            *(u16x8*)&sA[srow * 40 + schunk] = v0;
            *(u16x8*)&sA[(srow + 64) * 40 + schunk] = v1;
            *(u16x8*)&sA[128 * 40 + srow * 40 + schunk] = w0;
            *(u16x8*)&sA[128 * 40 + (srow + 64) * 40 + schunk] = w1;
        }
        {
            int n0 = bn + srow, n1 = bn + srow + 64;
            *(u16x8*)&sB[srow * 40 + schunk] = *(const u16x8*)&Bhi[(size_t)n0 * K + k0 + schunk];
            *(u16x8*)&sB[(srow + 64) * 40 + schunk] = *(const u16x8*)&Bhi[(size_t)n1 * K + k0 + schunk];
            *(u16x8*)&sB[128 * 40 + srow * 40 + schunk] = *(const u16x8*)&Blo[(size_t)n0 * K + k0 + schunk];
            *(u16x8*)&sB[128 * 40 + (srow + 64) * 40 + schunk] = *(const u16x8*)&Blo[(size_t)n1 * K + k0 + schunk];
        }
        __syncthreads();

        s16x8 af[4], al[4], bh[4], bl[4];
#pragma unroll
        for (int i = 0; i < 4; i++) {
            af[i] = __builtin_bit_cast(s16x8, *(const u16x8*)&sA[(wm + i * 16 + lr) * 40 + lg]);
            al[i] = __builtin_bit_cast(s16x8, *(const u16x8*)&sA[128 * 40 + (wm + i * 16 + lr) * 40 + lg]);
        }
#pragma unroll
        for (int j = 0; j < 4; j++) {
            bh[j] = __builtin_bit_cast(s16x8, *(const u16x8*)&sB[(wn + j * 16 + lr) * 40 + lg]);
            bl[j] = __builtin_bit_cast(s16x8, *(const u16x8*)&sB[128 * 40 + (wn + j * 16 + lr) * 40 + lg]);
        }
#pragma unroll
        for (int i = 0; i < 4; i++) {
#pragma unroll
            for (int j = 0; j < 4; j++) {
                acc[i][j] = __builtin_amdgcn_mfma_f32_16x16x32_bf16(af[i], bh[j], acc[i][j], 0, 0, 0);
                acc[i][j] = __builtin_amdgcn_mfma_f32_16x16x32_bf16(af[i], bl[j], acc[i][j], 0, 0, 0);
                acc[i][j] = __builtin_amdgcn_mfma_f32_16x16x32_bf16(al[i], bh[j], acc[i][j], 0, 0, 0);
            }
        }
        __syncthreads();
    }

    float bcol[4];
#pragma unroll
    for (int j = 0; j < 4; j++) bcol[j] = bias[bn + wn + j * 16 + lr];

    const int lq = (l >> 4) * 4;
#pragma unroll
    for (int i = 0; i < 4; i++) {
#pragma unroll
        for (int r0 = 0; r0 < 4; r0++) {
            int row = bm + wm + i * 16 + lq + r0;
            if (row < M) {
#pragma unroll
                for (int j = 0; j < 4; j++) {
                    float v = acc[i][j][r0] + bcol[j];
                    if (RELU) v = fmaxf(v, 0.f);
                    size_t idx = (size_t)row * NW + bn + wn + j * 16 + lr;
                    if (F32OUT) {
                        Cf[idx] = v;
                    } else {
                        u16 hv = f2bf(v);
                        Chi[idx] = hv;
                        Clo[idx] = f2bf(v - bf2f(hv));
                    }
                }
            }
        }
    }
}

// ---------------- launch ----------------
extern "C" void kernel_launch(void* const* d_in, const int* in_sizes, int n_in,
                              void* d_out, int out_size, void* d_ws, size_t ws_size,
                              hipStream_t stream) {
    const float* x   = (const float*)d_in[0];
    const int*   src = (const int*)d_in[1];
    const int*   dst = (const int*)d_in[2];
    const int*   bat = (const int*)d_in[3];
    const float* W1  = (const float*)d_in[4];  const float* b1  = (const float*)d_in[5];
    const float* W2  = (const float*)d_in[6];  const float* b2  = (const float*)d_in[7];
    const float* W3  = (const float*)d_in[8];  const float* b3  = (const float*)d_in[9];
    const float* Wm1 = (const float*)d_in[10]; const float* bm1 = (const float*)d_in[11];
    const float* Wm2 = (const float*)d_in[12]; const float* bm2 = (const float*)d_in[13];
    float* out = (float*)d_out;

    char* p = (char*)d_ws;
    auto carve = [&](size_t bytes) -> void* {
        void* r = (void*)p;
        p += (bytes + 511) & ~(size_t)511;
        return r;
    };
    u16*   x_bf    = (u16*)  carve((size_t)N_NODES * F_IN * 2);
    u16*   aggX    = (u16*)  carve((size_t)N_NODES * F_IN * 2);
    u16*   bufA    = (u16*)  carve((size_t)N_NODES * H * 2);
    u16*   bufB    = (u16*)  carve((size_t)N_NODES * H * 2);
    float* dinv    = (float*)carve((size_t)N_NODES * 4);
    int*   degc    = (int*)  carve((size_t)N_NODES * 4);
    int*   rowp    = (int*)  carve((size_t)(N_NODES + 1) * 4);
    int*   cur     = (int*)  carve((size_t)N_NODES * 4);
    int2*  ep      = (int2*) carve((size_t)N_EDGES * 8);
    int*   partial = (int*)  carve(4096);
    int*   goff    = (int*)  carve((size_t)(G_GR + 1) * 4);
    u16*   Wt1_hi  = (u16*)  carve((size_t)F_IN * H * 2);
    u16*   Wt1_lo  = (u16*)  carve((size_t)F_IN * H * 2);
    u16*   Wt2_hi  = (u16*)  carve((size_t)H * H * 2);
    u16*   Wt2_lo  = (u16*)  carve((size_t)H * H * 2);
    u16*   Wt3_hi  = (u16*)  carve((size_t)H * H * 2);
    u16*   Wt3_lo  = (u16*)  carve((size_t)H * H * 2);
    u16*   Wm1t_hi = (u16*)  carve((size_t)H * NHID * 2);
    u16*   Wm1t_lo = (u16*)  carve((size_t)H * NHID * 2);
    u16*   Wm2t_hi = (u16*)  carve((size_t)NHID * NOUT * 2);
    u16*   Wm2t_lo = (u16*)  carve((size_t)NHID * NOUT * 2);
    u16*   p_hi    = (u16*)  carve((size_t)G_GR * H * 2);
    u16*   p_lo    = (u16*)  carve((size_t)G_GR * H * 2);
    u16*   y_hi    = (u16*)  carve((size_t)G_GR * H * 2);
    u16*   y_lo    = (u16*)  carve((size_t)G_GR * H * 2);
    u16*   hd_hi   = (u16*)  carve((size_t)G_GR * NHID * 2);
    u16*   hd_lo   = (u16*)  carve((size_t)G_GR * NHID * 2);
    float* poolacc = (float*)carve((size_t)G_GR * H * 4);

    const int NB = (N_NODES + 255) / 256;

    hipMemsetAsync(degc, 0, (size_t)N_NODES * 4, stream);
    hipMemsetAsync(poolacc, 0, (size_t)G_GR * H * 4, stream);
    prep_head<<<HEAD_BLKS, 256, 0, stream>>>(dst, degc,
                                             W1, Wt1_hi, Wt1_lo,
                                             W2, Wt2_hi, Wt2_lo,
                                             W3, Wt3_hi, Wt3_lo,
                                             Wm1, Wm1t_hi, Wm1t_lo,
                                             Wm2, Wm2t_hi, Wm2t_lo, bat, goff);
    scan_partial<<<NB, 256, 0, stream>>>(degc, partial);
    scan_offsets<<<1, 512, 0, stream>>>(partial, NB, rowp);
    scan_final_dinv<<<NB, 256, 0, stream>>>(degc, partial, rowp, cur, dinv);
    // scatter (R8 strided form) + split_x freight (both LDS-free; scatter blocks first)
    scatter_splitx<<<CD_BLKS + SPX_BLKS, 256, 0, stream>>>(src, dst, dinv, cur, ep, x, x_bf);

    dim3 ggrid((N_NODES + 127) / 128, 2);

    // layer 1: aggregate-first (256B rows), then transform+bias+relu
    gcn_agg128<<<N_NODES / 16, 256, 0, stream>>>(x_bf, rowp, ep, dinv, aggX);
    gemm_bias<F_IN, true><<<ggrid, 256, 0, stream>>>(aggX, Wt1_hi, Wt1_lo, b1, bufA, N_NODES);
    // layer 2
    gcn_agg256<<<N_NODES / 8, 256, 0, stream>>>(bufA, rowp, ep, dinv, bufB);
    gemm_bias<H, true><<<ggrid, 256, 0, stream>>>(bufB, Wt2_hi, Wt2_lo, b2, bufA, N_NODES);
    // layer 3 + pool fused (gather form): per-node f32 row -> LDS -> per-graph atomic flush
    gcn_agg_pool<<<N_NODES / 8, 256, 0, stream>>>(bufA, rowp, ep, dinv, bat, poolacc);
    pool_finalize2<<<G_GR, 256, 0, stream>>>(poolacc, goff, p_hi, p_lo);

    // tail: y=pW3+b3 -> hidden=relu(yWm1+bm1) -> out=hidden Wm2+bm2
    dim3 g3(2, 2), gm1(2, 4), gm2(2, 2);
    gemm_split<H, H, false, false><<<g3, 256, 0, stream>>>(
        p_hi, p_lo, Wt3_hi, Wt3_lo, b3, y_hi, y_lo, nullptr, G_GR);
    gemm_split<H, NHID, true, false><<<gm1, 256, 0, stream>>>(
        y_hi, y_lo, Wm1t_hi, Wm1t_lo, bm1, hd_hi, hd_lo, nullptr, G_GR);
    gemm_split<NHID, NOUT, false, true><<<gm2, 256, 0, stream>>>(
        hd_hi, hd_lo, Wm2t_hi, Wm2t_lo, bm2, nullptr, nullptr, out, G_GR);
}

// Round 3
// 693.837 us; speedup vs baseline: 4.5289x; 1.0440x over previous
//
#include <hip/hip_runtime.h>
#include <hip/hip_bf16.h>

#define N_NODES 100000
#define N_EDGES 1600000
#define F_IN    128
#define H       256
#define NHID    512
#define NOUT    256
#define G_GR    256

typedef unsigned short u16;
typedef unsigned int u32;
typedef __attribute__((ext_vector_type(8))) short s16x8;
typedef __attribute__((ext_vector_type(8))) unsigned short u16x8;
typedef __attribute__((ext_vector_type(4))) float f32x4;

// edge entry encoding: (src:17b | indeg_src:15b). indeg is ~Poisson(16) for this
// input (max ~50), far below 2^15. wt is recomputed as dinv[dst]*rsqrtf(1+deg) —
// bit-identical to the old stored product (same rsqrtf, same f32 mul).
#define SRC_MASK 0x1FFFFu
#define DEG_SHIFT 17

__device__ __forceinline__ float bf2f(u16 u) {
    union { unsigned int i; float f; } v; v.i = ((unsigned int)u) << 16; return v.f;
}
__device__ __forceinline__ u16 f2bf(float f) {
    union { float f; unsigned int i; } v; v.f = f;
    unsigned int x = v.i;
    x += 0x7fffu + ((x >> 16) & 1u);
    return (u16)(x >> 16);
}

// ---------------- head: count_deg (atomics) + LDS-tiled weight transposes + goff -----
#define CD_BLKS   1563                        // 4 strided edges/thread (R8 known-good form)
#define SPX_BLKS  ((N_NODES * F_IN) / 1024)   // 12500 — carried by scatter kernel
#define T1_TILES  ((F_IN / 64) * (H / 64))    // 8
#define T2_TILES  ((H / 64) * (H / 64))       // 16
#define T3_TILES  ((H / 64) * (H / 64))       // 16
#define TM1_TILES ((H / 64) * (NHID / 64))    // 32
#define TM2_TILES ((NHID / 64) * (NOUT / 64)) // 32
#define HEAD_BLKS (CD_BLKS + T1_TILES + T2_TILES + T3_TILES + TM1_TILES + TM2_TILES + 2)

// 64x64 tile transpose via padded LDS: coalesced f32 reads, coalesced 2B hi/lo stores.
__device__ __forceinline__ void transpose_tile(float (*tile)[65],
        const float* __restrict__ W, u16* __restrict__ thi, u16* __restrict__ tlo,
        int K, int N, int tileIdx) {
    const int ntn = N >> 6;
    const int tk = tileIdx / ntn, tn = tileIdx - tk * ntn;
    const int t = threadIdx.x;
    const int c = t & 63, r4 = t >> 6;
#pragma unroll
    for (int i = 0; i < 64; i += 4)
        tile[r4 + i][c] = W[(size_t)(tk * 64 + r4 + i) * N + tn * 64 + c];
    __syncthreads();
#pragma unroll
    for (int i = 0; i < 64; i += 4) {
        int n = tn * 64 + r4 + i, k = tk * 64 + c;
        float f = tile[c][r4 + i];
        u16 h = f2bf(f);
        thi[(size_t)n * K + k] = h;
        tlo[(size_t)n * K + k] = f2bf(f - bf2f(h));
    }
}

__global__ __launch_bounds__(256) void prep_head(
        const int* __restrict__ dst, int* __restrict__ degc,
        const float* __restrict__ W1, u16* __restrict__ t1h, u16* __restrict__ t1l,
        const float* __restrict__ W2, u16* __restrict__ t2h, u16* __restrict__ t2l,
        const float* __restrict__ W3, u16* __restrict__ t3h, u16* __restrict__ t3l,
        const float* __restrict__ Wm1, u16* __restrict__ tm1h, u16* __restrict__ tm1l,
        const float* __restrict__ Wm2, u16* __restrict__ tm2h, u16* __restrict__ tm2l,
        const int* __restrict__ batch, int* __restrict__ goff) {
    __shared__ float tile[64][65];
    int bid = blockIdx.x;
    if (bid < CD_BLKS) {
        int base = bid * 1024 + threadIdx.x;
#pragma unroll
        for (int q = 0; q < 4; q++) {
            int e = base + q * 256;
            if (e < N_EDGES) atomicAdd(&degc[dst[e]], 1);
        }
        return;
    }
    bid -= CD_BLKS;
    if (bid < T1_TILES) { transpose_tile(tile, W1, t1h, t1l, F_IN, H, bid); return; }
    bid -= T1_TILES;
    if (bid < T2_TILES) { transpose_tile(tile, W2, t2h, t2l, H, H, bid); return; }
    bid -= T2_TILES;
    if (bid < T3_TILES) { transpose_tile(tile, W3, t3h, t3l, H, H, bid); return; }
    bid -= T3_TILES;
    if (bid < TM1_TILES) { transpose_tile(tile, Wm1, tm1h, tm1l, H, NHID, bid); return; }
    bid -= TM1_TILES;
    if (bid < TM2_TILES) { transpose_tile(tile, Wm2, tm2h, tm2l, NHID, NOUT, bid); return; }
    bid -= TM2_TILES;
    {
        int g = bid * 256 + threadIdx.x;
        if (g > G_GR) return;
        int lo = 0, hi = N_NODES;
        while (lo < hi) {
            int mid = (lo + hi) >> 1;
            if (batch[mid] < g) lo = mid + 1; else hi = mid;
        }
        goff[g] = lo;
    }
}

// ---------------- scan (CSR rowp) ----------------
__global__ void scan_partial(const int* __restrict__ cnt, int* __restrict__ partial) {
    __shared__ int s[256];
    int t = threadIdx.x;
    int i = blockIdx.x * 256 + t;
    int v = (i < N_NODES) ? cnt[i] : 0;
    s[t] = v; __syncthreads();
    for (int off = 128; off > 0; off >>= 1) {
        if (t < off) s[t] += s[t + off];
        __syncthreads();
    }
    if (t == 0) partial[blockIdx.x] = s[0];
}

__global__ void scan_offsets(int* __restrict__ partial, int nb, int* __restrict__ rowp) {
    __shared__ int s[512];
    int t = threadIdx.x;
    int orig = (t < nb) ? partial[t] : 0;
    s[t] = orig; __syncthreads();
    for (int off = 1; off < 512; off <<= 1) {
        int u = (t >= off) ? s[t - off] : 0;
        __syncthreads();
        s[t] += u;
        __syncthreads();
    }
    if (t < nb) partial[t] = s[t] - orig;
    if (t == 0) rowp[N_NODES] = N_EDGES;
}

__global__ void scan_final_dinv(const int* __restrict__ cnt, const int* __restrict__ partial,
                                int* __restrict__ rowp, int* __restrict__ cur,
                                float* __restrict__ dinv, u32* __restrict__ pack) {
    __shared__ int s[256];
    int t = threadIdx.x;
    int i = blockIdx.x * 256 + t;
    int v = (i < N_NODES) ? cnt[i] : 0;
    s[t] = v; __syncthreads();
    for (int off = 1; off < 256; off <<= 1) {
        int u = (t >= off) ? s[t - off] : 0;
        __syncthreads();
        s[t] += u;
        __syncthreads();
    }
    if (i < N_NODES) {
        int r = partial[blockIdx.x] + s[t] - v;
        rowp[i] = r;
        cur[i] = r;
        dinv[i] = rsqrtf(1.0f + (float)v);
        pack[i] = (u32)i | ((u32)v << DEG_SHIFT);
    }
}

// ---------------- scatter (packed 4B entries) + split_x streaming freight ----------------
__global__ __launch_bounds__(256) void scatter_splitx(
        const int* __restrict__ src, const int* __restrict__ dst,
        const u32* __restrict__ pack, int* __restrict__ cur,
        u32* __restrict__ ep4,
        const float* __restrict__ x, u16* __restrict__ x_bf) {
    int bid = blockIdx.x;
    if (bid < CD_BLKS) {
        int base = bid * 1024 + threadIdx.x;
#pragma unroll
        for (int q = 0; q < 4; q++) {
            int e = base + q * 256;
            if (e < N_EDGES) {
                int d = dst[e];
                int s = src[e];
                u32 pk = pack[s];
                int pos = atomicAdd(&cur[d], 1);
                ep4[pos] = pk;
            }
        }
        return;
    }
    bid -= CD_BLKS;
    {   // split_x: 4 floats/thread, 12500 blocks
        int idx = bid * 256 + threadIdx.x;
        float4 f = *(const float4*)&x[(size_t)idx * 4];
        ushort4 o;
        o.x = f2bf(f.x); o.y = f2bf(f.y); o.z = f2bf(f.z); o.w = f2bf(f.w);
        *(ushort4*)&x_bf[(size_t)idx * 4] = o;
    }
}

// ---------------- aggregation: half-wave (32 lanes x ushort8) per node, H=256 ----------------
__global__ __launch_bounds__(256) void gcn_agg256(
        const u16* __restrict__ in, const int* __restrict__ rowp,
        const u32* __restrict__ ep4, const float* __restrict__ dinv,
        u16* __restrict__ outp) {
    int node = blockIdx.x * 8 + (threadIdx.x >> 5);
    int l = threadIdx.x & 31;
    int beg = rowp[node], end = rowp[node + 1];
    float dnode = dinv[node];
    float a[8] = {};
    int e = beg;
    u32 pr[8];
    bool have = (e + 8 <= end);
    if (have) {
#pragma unroll
        for (int q = 0; q < 8; q++) pr[q] = ep4[e + q];
    }
    while (have) {
        u32 g8[8];
#pragma unroll
        for (int q = 0; q < 8; q++) g8[q] = pr[q];
        int en = e + 8;
        bool haven = (en + 8 <= end);
        if (haven) {
#pragma unroll
            for (int q = 0; q < 8; q++) pr[q] = ep4[en + q];
        }
#pragma unroll
        for (int q = 0; q < 8; q++) {
            u16x8 u = *(const u16x8*)&in[(size_t)(g8[q] & SRC_MASK) * H + l * 8];
            float wt = dnode * rsqrtf(1.0f + (float)(g8[q] >> DEG_SHIFT));
#pragma unroll
            for (int r = 0; r < 8; r++) a[r] += bf2f(u[r]) * wt;
        }
        e = en; have = haven;
    }
    for (; e < end; e++) {
        u32 pe = ep4[e];
        float wt = dnode * rsqrtf(1.0f + (float)(pe >> DEG_SHIFT));
        u16x8 u = *(const u16x8*)&in[(size_t)(pe & SRC_MASK) * H + l * 8];
#pragma unroll
        for (int r = 0; r < 8; r++) a[r] += bf2f(u[r]) * wt;
    }
    u16x8 us = *(const u16x8*)&in[(size_t)node * H + l * 8];
    float dd = dnode * dnode;
    u16x8 o;
#pragma unroll
    for (int r = 0; r < 8; r++) o[r] = f2bf(a[r] + bf2f(us[r]) * dd);
    *(u16x8*)&outp[(size_t)node * H + l * 8] = o;
}

// ---------------- aggregation: quarter-wave (16 lanes x ushort8) per node, F=128 ----------------
__global__ __launch_bounds__(256) void gcn_agg128(
        const u16* __restrict__ in, const int* __restrict__ rowp,
        const u32* __restrict__ ep4, const float* __restrict__ dinv,
        u16* __restrict__ outp) {
    int node = blockIdx.x * 16 + (threadIdx.x >> 4);
    int l = threadIdx.x & 15;
    int beg = rowp[node], end = rowp[node + 1];
    float dnode = dinv[node];
    float a[8] = {};
    int e = beg;
    u32 pr[8];
    bool have = (e + 8 <= end);
    if (have) {
#pragma unroll
        for (int q = 0; q < 8; q++) pr[q] = ep4[e + q];
    }
    while (have) {
        u32 g8[8];
#pragma unroll
        for (int q = 0; q < 8; q++) g8[q] = pr[q];
        int en = e + 8;
        bool haven = (en + 8 <= end);
        if (haven) {
#pragma unroll
            for (int q = 0; q < 8; q++) pr[q] = ep4[en + q];
        }
#pragma unroll
        for (int q = 0; q < 8; q++) {
            u16x8 u = *(const u16x8*)&in[(size_t)(g8[q] & SRC_MASK) * F_IN + l * 8];
            float wt = dnode * rsqrtf(1.0f + (float)(g8[q] >> DEG_SHIFT));
#pragma unroll
            for (int r = 0; r < 8; r++) a[r] += bf2f(u[r]) * wt;
        }
        e = en; have = haven;
    }
    for (; e < end; e++) {
        u32 pe = ep4[e];
        float wt = dnode * rsqrtf(1.0f + (float)(pe >> DEG_SHIFT));
        u16x8 u = *(const u16x8*)&in[(size_t)(pe & SRC_MASK) * F_IN + l * 8];
#pragma unroll
        for (int r = 0; r < 8; r++) a[r] += bf2f(u[r]) * wt;
    }
    u16x8 us = *(const u16x8*)&in[(size_t)node * F_IN + l * 8];
    float dd = dnode * dnode;
    u16x8 o;
#pragma unroll
    for (int r = 0; r < 8; r++) o[r] = f2bf(a[r] + bf2f(us[r]) * dd);
    *(u16x8*)&outp[(size_t)node * F_IN + l * 8] = o;
}

// ---------------- layer-3 fused agg+pool: gather form, no per-node output ----------------
__global__ __launch_bounds__(256) void gcn_agg_pool(
        const u16* __restrict__ in, const int* __restrict__ rowp,
        const u32* __restrict__ ep4, const float* __restrict__ dinv,
        const int* __restrict__ batch, float* __restrict__ poolacc) {
    __shared__ __align__(16) float pacc[8][H];
    __shared__ int gslot[8];
    const int tid = threadIdx.x;
    const int hw = tid >> 5;
    const int l = tid & 31;
    const int node = blockIdx.x * 8 + hw;
    const int gbase = batch[blockIdx.x * 8];

    int beg = rowp[node], end = rowp[node + 1];
    float dnode = dinv[node];
    float a[8] = {};
    int e = beg;
    u32 pr[8];
    bool have = (e + 8 <= end);
    if (have) {
#pragma unroll
        for (int q = 0; q < 8; q++) pr[q] = ep4[e + q];
    }
    while (have) {
        u32 g8[8];
#pragma unroll
        for (int q = 0; q < 8; q++) g8[q] = pr[q];
        int en = e + 8;
        bool haven = (en + 8 <= end);
        if (haven) {
#pragma unroll
            for (int q = 0; q < 8; q++) pr[q] = ep4[en + q];
        }
#pragma unroll
        for (int q = 0; q < 8; q++) {
            u16x8 u = *(const u16x8*)&in[(size_t)(g8[q] & SRC_MASK) * H + l * 8];
            float wt = dnode * rsqrtf(1.0f + (float)(g8[q] >> DEG_SHIFT));
#pragma unroll
            for (int r = 0; r < 8; r++) a[r] += bf2f(u[r]) * wt;
        }
        e = en; have = haven;
    }
    for (; e < end; e++) {
        u32 pe = ep4[e];
        float wt = dnode * rsqrtf(1.0f + (float)(pe >> DEG_SHIFT));
        u16x8 u = *(const u16x8*)&in[(size_t)(pe & SRC_MASK) * H + l * 8];
#pragma unroll
        for (int r = 0; r < 8; r++) a[r] += bf2f(u[r]) * wt;
    }
    u16x8 us = *(const u16x8*)&in[(size_t)node * H + l * 8];
    float dd = dnode * dnode;
    f32x4 lo4, hi4;
#pragma unroll
    for (int r = 0; r < 4; r++) lo4[r] = a[r] + bf2f(us[r]) * dd;
#pragma unroll
    for (int r = 0; r < 4; r++) hi4[r] = a[r + 4] + bf2f(us[r + 4]) * dd;
    *(f32x4*)&pacc[hw][l * 8] = lo4;
    *(f32x4*)&pacc[hw][l * 8 + 4] = hi4;
    if (l == 0) gslot[hw] = batch[node] - gbase;
    __syncthreads();

    // reduce 8 node-rows by graph slot, flush with global f32 atomics
    int smax = gslot[7];          // batch sorted -> slots non-decreasing
    float v[8];
#pragma unroll
    for (int q = 0; q < 8; q++) v[q] = pacc[q][tid];
    for (int s = 0; s <= smax; s++) {
        float acc = 0.f;
#pragma unroll
        for (int q = 0; q < 8; q++)
            if (gslot[q] == s) acc += v[q];
        atomicAdd(&poolacc[(size_t)(gbase + s) * H + tid], acc);
    }
}

// ---------------- pool finalize: divide by counts, hi/lo bf16 split ----------------
__global__ __launch_bounds__(256) void pool_finalize2(
        const float* __restrict__ poolacc, const int* __restrict__ goff,
        u16* __restrict__ phi, u16* __restrict__ plo) {
    int g = blockIdx.x, t = threadIdx.x;
    float c = (float)(goff[g + 1] - goff[g]);
    float acc = poolacc[(size_t)g * H + t] / fmaxf(c, 1.f);
    u16 hv = f2bf(acc);
    phi[g * H + t] = hv;
    plo[g * H + t] = f2bf(acc - bf2f(hv));
}

// ---------------- MFMA GEMM with bias(+relu) epilogue (node layers) ----------------
template<int K, bool RELU>
__global__ __launch_bounds__(256) void gemm_bias(
        const u16* __restrict__ A,
        const u16* __restrict__ Bhi, const u16* __restrict__ Blo,
        const float* __restrict__ bias, u16* __restrict__ C, int M) {
    __shared__ __align__(16) u16 sA[128 * 40];
    __shared__ __align__(16) u16 sB[2 * 128 * 40];
    const int tid = threadIdx.x;
    const int w = tid >> 6, l = tid & 63;
    const int wm = (w & 1) * 64, wn = (w >> 1) * 64;
    const int bm = blockIdx.x * 128, bn = blockIdx.y * 128;
    const int srow = tid >> 2;
    const int schunk = (tid & 3) * 8;
    const int lr = l & 15, lg = (l >> 4) * 8;

    f32x4 acc[4][4] = {};

    for (int k0 = 0; k0 < K; k0 += 32) {
        {
            int r0 = bm + srow, r1 = bm + srow + 64;
            u16x8 v0 = {}, v1 = {};
            if (r0 < M) v0 = *(const u16x8*)&A[(size_t)r0 * K + k0 + schunk];
            if (r1 < M) v1 = *(const u16x8*)&A[(size_t)r1 * K + k0 + schunk];
            *(u16x8*)&sA[srow * 40 + schunk] = v0;
            *(u16x8*)&sA[(srow + 64) * 40 + schunk] = v1;
        }
        {
            int n0 = bn + srow, n1 = bn + srow + 64;
            *(u16x8*)&sB[srow * 40 + schunk] = *(const u16x8*)&Bhi[(size_t)n0 * K + k0 + schunk];
            *(u16x8*)&sB[(srow + 64) * 40 + schunk] = *(const u16x8*)&Bhi[(size_t)n1 * K + k0 + schunk];
            *(u16x8*)&sB[128 * 40 + srow * 40 + schunk] = *(const u16x8*)&Blo[(size_t)n0 * K + k0 + schunk];
            *(u16x8*)&sB[128 * 40 + (srow + 64) * 40 + schunk] = *(const u16x8*)&Blo[(size_t)n1 * K + k0 + schunk];
        }
        __syncthreads();

        s16x8 af[4], bh[4], bl[4];
#pragma unroll
        for (int i = 0; i < 4; i++)
            af[i] = __builtin_bit_cast(s16x8, *(const u16x8*)&sA[(wm + i * 16 + lr) * 40 + lg]);
#pragma unroll
        for (int j = 0; j < 4; j++) {
            bh[j] = __builtin_bit_cast(s16x8, *(const u16x8*)&sB[(wn + j * 16 + lr) * 40 + lg]);
            bl[j] = __builtin_bit_cast(s16x8, *(const u16x8*)&sB[128 * 40 + (wn + j * 16 + lr) * 40 + lg]);
        }
#pragma unroll
        for (int i = 0; i < 4; i++) {
#pragma unroll
            for (int j = 0; j < 4; j++) {
                acc[i][j] = __builtin_amdgcn_mfma_f32_16x16x32_bf16(af[i], bh[j], acc[i][j], 0, 0, 0);
                acc[i][j] = __builtin_amdgcn_mfma_f32_16x16x32_bf16(af[i], bl[j], acc[i][j], 0, 0, 0);
            }
        }
        __syncthreads();
    }

    float bcol[4];
#pragma unroll
    for (int j = 0; j < 4; j++) bcol[j] = bias[bn + wn + j * 16 + lr];

    const int lq = (l >> 4) * 4;
#pragma unroll
    for (int i = 0; i < 4; i++) {
#pragma unroll
        for (int r0 = 0; r0 < 4; r0++) {
            int row = bm + wm + i * 16 + lq + r0;
            if (row < M) {
#pragma unroll
                for (int j = 0; j < 4; j++) {
                    float v = acc[i][j][r0] + bcol[j];
                    if (RELU) v = fmaxf(v, 0.f);
                    C[(size_t)row * H + bn + wn + j * 16 + lr] = f2bf(v);
                }
            }
        }
    }
}

// ---------------- split-precision MFMA GEMM (MLP tail) ----------------
template<int K, int NW, bool RELU, bool F32OUT>
__global__ __launch_bounds__(256) void gemm_split(
        const u16* __restrict__ Ahi, const u16* __restrict__ Alo,
        const u16* __restrict__ Bhi, const u16* __restrict__ Blo,
        const float* __restrict__ bias,
        u16* __restrict__ Chi, u16* __restrict__ Clo, float* __restrict__ Cf,
        int M) {
    __shared__ __align__(16) u16 sA[2 * 128 * 40];
    __shared__ __align__(16) u16 sB[2 * 128 * 40];
    const int tid = threadIdx.x;
    const int w = tid >> 6, l = tid & 63;
    const int wm = (w & 1) * 64, wn = (w >> 1) * 64;
    const int bm = blockIdx.x * 128, bn = blockIdx.y * 128;
    const int srow = tid >> 2;
    const int schunk = (tid & 3) * 8;
    const int lr = l & 15, lg = (l >> 4) * 8;

    f32x4 acc[4][4] = {};

    for (int k0 = 0; k0 < K; k0 += 32) {
        {
            int r0 = bm + srow, r1 = bm + srow + 64;
            u16x8 v0 = {}, v1 = {}, w0 = {}, w1 = {};
            if (r0 < M) {
                v0 = *(const u16x8*)&Ahi[(size_t)r0 * K + k0 + schunk];
                w0 = *(const u16x8*)&Alo[(size_t)r0 * K + k0 + schunk];
            }
            if (r1 < M) {
                v1 = *(const u16x8*)&Ahi[(size_t)r1 * K + k0 + schunk];
                w1 = *(const u16x8*)&Alo[(size_t)r1 * K + k0 + schunk];
            }
            *(u16x8*)&sA[srow * 40 + schunk] = v0;
            *(u16x8*)&sA[(srow + 64) * 40 + schunk] = v1;
            *(u16x8*)&sA[128 * 40 + srow * 40 + schunk] = w0;
            *(u16x8*)&sA[128 * 40 + (srow + 64) * 40 + schunk] = w1;
        }
        {
            int n0 = bn + srow, n1 = bn + srow + 64;
            *(u16x8*)&sB[srow * 40 + schunk] = *(const u16x8*)&Bhi[(size_t)n0 * K + k0 + schunk];
            *(u16x8*)&sB[(srow + 64) * 40 + schunk] = *(const u16x8*)&Bhi[(size_t)n1 * K + k0 + schunk];
            *(u16x8*)&sB[128 * 40 + srow * 40 + schunk] = *(const u16x8*)&Blo[(size_t)n0 * K + k0 + schunk];
            *(u16x8*)&sB[128 * 40 + (srow + 64) * 40 + schunk] = *(const u16x8*)&Blo[(size_t)n1 * K + k0 + schunk];
        }
        __syncthreads();

        s16x8 af[4], al[4], bh[4], bl[4];
#pragma unroll
        for (int i = 0; i < 4; i++) {
            af[i] = __builtin_bit_cast(s16x8, *(const u16x8*)&sA[(wm + i * 16 + lr) * 40 + lg]);
            al[i] = __builtin_bit_cast(s16x8, *(const u16x8*)&sA[128 * 40 + (wm + i * 16 + lr) * 40 + lg]);
        }
#pragma unroll
        for (int j = 0; j < 4; j++) {
            bh[j] = __builtin_bit_cast(s16x8, *(const u16x8*)&sB[(wn + j * 16 + lr) * 40 + lg]);
            bl[j] = __builtin_bit_cast(s16x8, *(const u16x8*)&sB[128 * 40 + (wn + j * 16 + lr) * 40 + lg]);
        }
#pragma unroll
        for (int i = 0; i < 4; i++) {
#pragma unroll
            for (int j = 0; j < 4; j++) {
                acc[i][j] = __builtin_amdgcn_mfma_f32_16x16x32_bf16(af[i], bh[j], acc[i][j], 0, 0, 0);
                acc[i][j] = __builtin_amdgcn_mfma_f32_16x16x32_bf16(af[i], bl[j], acc[i][j], 0, 0, 0);
                acc[i][j] = __builtin_amdgcn_mfma_f32_16x16x32_bf16(al[i], bh[j], acc[i][j], 0, 0, 0);
            }
        }
        __syncthreads();
    }

    float bcol[4];
#pragma unroll
    for (int j = 0; j < 4; j++) bcol[j] = bias[bn + wn + j * 16 + lr];

    const int lq = (l >> 4) * 4;
#pragma unroll
    for (int i = 0; i < 4; i++) {
#pragma unroll
        for (int r0 = 0; r0 < 4; r0++) {
            int row = bm + wm + i * 16 + lq + r0;
            if (row < M) {
#pragma unroll
                for (int j = 0; j < 4; j++) {
                    float v = acc[i][j][r0] + bcol[j];
                    if (RELU) v = fmaxf(v, 0.f);
                    size_t idx = (size_t)row * NW + bn + wn + j * 16 + lr;
                    if (F32OUT) {
                        Cf[idx] = v;
                    } else {
                        u16 hv = f2bf(v);
                        Chi[idx] = hv;
                        Clo[idx] = f2bf(v - bf2f(hv));
                    }
                }
            }
        }
    }
}

// ---------------- launch ----------------
extern "C" void kernel_launch(void* const* d_in, const int* in_sizes, int n_in,
                              void* d_out, int out_size, void* d_ws, size_t ws_size,
                              hipStream_t stream) {
    const float* x   = (const float*)d_in[0];
    const int*   src = (const int*)d_in[1];
    const int*   dst = (const int*)d_in[2];
    const int*   bat = (const int*)d_in[3];
    const float* W1  = (const float*)d_in[4];  const float* b1  = (const float*)d_in[5];
    const float* W2  = (const float*)d_in[6];  const float* b2  = (const float*)d_in[7];
    const float* W3  = (const float*)d_in[8];  const float* b3  = (const float*)d_in[9];
    const float* Wm1 = (const float*)d_in[10]; const float* bm1 = (const float*)d_in[11];
    const float* Wm2 = (const float*)d_in[12]; const float* bm2 = (const float*)d_in[13];
    float* out = (float*)d_out;

    char* p = (char*)d_ws;
    auto carve = [&](size_t bytes) -> void* {
        void* r = (void*)p;
        p += (bytes + 511) & ~(size_t)511;
        return r;
    };
    u16*   x_bf    = (u16*)  carve((size_t)N_NODES * F_IN * 2);
    u16*   aggX    = (u16*)  carve((size_t)N_NODES * F_IN * 2);
    u16*   bufA    = (u16*)  carve((size_t)N_NODES * H * 2);
    u16*   bufB    = (u16*)  carve((size_t)N_NODES * H * 2);
    float* dinv    = (float*)carve((size_t)N_NODES * 4);
    int*   degc    = (int*)  carve((size_t)N_NODES * 4);
    int*   rowp    = (int*)  carve((size_t)(N_NODES + 1) * 4);
    int*   cur     = (int*)  carve((size_t)N_NODES * 4);
    u32*   ep4     = (u32*)  carve((size_t)N_EDGES * 4);
    u32*   pack    = (u32*)  carve((size_t)N_NODES * 4);
    int*   partial = (int*)  carve(4096);
    int*   goff    = (int*)  carve((size_t)(G_GR + 1) * 4);
    u16*   Wt1_hi  = (u16*)  carve((size_t)F_IN * H * 2);
    u16*   Wt1_lo  = (u16*)  carve((size_t)F_IN * H * 2);
    u16*   Wt2_hi  = (u16*)  carve((size_t)H * H * 2);
    u16*   Wt2_lo  = (u16*)  carve((size_t)H * H * 2);
    u16*   Wt3_hi  = (u16*)  carve((size_t)H * H * 2);
    u16*   Wt3_lo  = (u16*)  carve((size_t)H * H * 2);
    u16*   Wm1t_hi = (u16*)  carve((size_t)H * NHID * 2);
    u16*   Wm1t_lo = (u16*)  carve((size_t)H * NHID * 2);
    u16*   Wm2t_hi = (u16*)  carve((size_t)NHID * NOUT * 2);
    u16*   Wm2t_lo = (u16*)  carve((size_t)NHID * NOUT * 2);
    u16*   p_hi    = (u16*)  carve((size_t)G_GR * H * 2);
    u16*   p_lo    = (u16*)  carve((size_t)G_GR * H * 2);
    u16*   y_hi    = (u16*)  carve((size_t)G_GR * H * 2);
    u16*   y_lo    = (u16*)  carve((size_t)G_GR * H * 2);
    u16*   hd_hi   = (u16*)  carve((size_t)G_GR * NHID * 2);
    u16*   hd_lo   = (u16*)  carve((size_t)G_GR * NHID * 2);
    float* poolacc = (float*)carve((size_t)G_GR * H * 4);

    const int NB = (N_NODES + 255) / 256;

    hipMemsetAsync(degc, 0, (size_t)N_NODES * 4, stream);
    hipMemsetAsync(poolacc, 0, (size_t)G_GR * H * 4, stream);
    prep_head<<<HEAD_BLKS, 256, 0, stream>>>(dst, degc,
                                             W1, Wt1_hi, Wt1_lo,
                                             W2, Wt2_hi, Wt2_lo,
                                             W3, Wt3_hi, Wt3_lo,
                                             Wm1, Wm1t_hi, Wm1t_lo,
                                             Wm2, Wm2t_hi, Wm2t_lo, bat, goff);
    scan_partial<<<NB, 256, 0, stream>>>(degc, partial);
    scan_offsets<<<1, 512, 0, stream>>>(partial, NB, rowp);
    scan_final_dinv<<<NB, 256, 0, stream>>>(degc, partial, rowp, cur, dinv, pack);
    // scatter (packed 4B entries) + split_x freight
    scatter_splitx<<<CD_BLKS + SPX_BLKS, 256, 0, stream>>>(src, dst, pack, cur, ep4, x, x_bf);

    dim3 ggrid((N_NODES + 127) / 128, 2);

    // layer 1: aggregate-first (256B rows), then transform+bias+relu
    gcn_agg128<<<N_NODES / 16, 256, 0, stream>>>(x_bf, rowp, ep4, dinv, aggX);
    gemm_bias<F_IN, true><<<ggrid, 256, 0, stream>>>(aggX, Wt1_hi, Wt1_lo, b1, bufA, N_NODES);
    // layer 2
    gcn_agg256<<<N_NODES / 8, 256, 0, stream>>>(bufA, rowp, ep4, dinv, bufB);
    gemm_bias<H, true><<<ggrid, 256, 0, stream>>>(bufB, Wt2_hi, Wt2_lo, b2, bufA, N_NODES);
    // layer 3 + pool fused (gather form): per-node f32 row -> LDS -> per-graph atomic flush
    gcn_agg_pool<<<N_NODES / 8, 256, 0, stream>>>(bufA, rowp, ep4, dinv, bat, poolacc);
    pool_finalize2<<<G_GR, 256, 0, stream>>>(poolacc, goff, p_hi, p_lo);

    // tail: y=pW3+b3 -> hidden=relu(yWm1+bm1) -> out=hidden Wm2+bm2
    dim3 g3(2, 2), gm1(2, 4), gm2(2, 2);
    gemm_split<H, H, false, false><<<g3, 256, 0, stream>>>(
        p_hi, p_lo, Wt3_hi, Wt3_lo, b3, y_hi, y_lo, nullptr, G_GR);
    gemm_split<H, NHID, true, false><<<gm1, 256, 0, stream>>>(
        y_hi, y_lo, Wm1t_hi, Wm1t_lo, bm1, hd_hi, hd_lo, nullptr, G_GR);
    gemm_split<NHID, NOUT, false, true><<<gm2, 256, 0, stream>>>(
        hd_hi, hd_lo, Wm2t_hi, Wm2t_lo, bm2, nullptr, nullptr, out, G_GR);
}